// Round 6
// baseline (375.538 us; speedup 1.0000x reference)
//
#include <hip/hip_runtime.h>
#include <math.h>

#define NUM_V 512
#define NUM_F 1024
#define IMG_H 256
#define NCHUNK 16
#define FPC (NUM_F/NCHUNK)        // 64 faces per chunk
#define TAN_T 0.57735026919f      // tan(30 deg)
#define LOG_EPS  -13.8155106f     // log(1e-6)
// Edge constants pre-scaled by 100 = sqrt(1/SIGMA), so s = d'*|d'| directly.
#define DCULL_S  -3.72f           // scaled dist <= -3.72 => |term| < 1e-6

// Workspace layout (floats unless noted):
//   slices  [256*NCHUNK][256]   sparse-written (only chunks with n>0, c>=1)
//   cnt     [256*NCHUNK] int    release-stored n+1 (>=1) when chunk done
//   tileSSE [256]               per-tile SSE
//   tileFlag[256] int           release-stored 1 when tileSSE valid
// Poison 0xAAAAAAAA is negative as int => "<1" reliably means not-ready.

__device__ __forceinline__ void st_release(int* p, int v) {
    __hip_atomic_store(p, v, __ATOMIC_RELEASE, __HIP_MEMORY_SCOPE_AGENT);
}
__device__ __forceinline__ int ld_acquire(const int* p) {
    return __hip_atomic_load(p, __ATOMIC_ACQUIRE, __HIP_MEMORY_SCOPE_AGENT);
}

// ---------------------------------------------------------------------------
// Single fused kernel. Grid = 256 tiles x NCHUNK chunks (chunk fast-varying).
// All blocks: project verts, build scaled edge constants for their chunk,
// cull vs tile rect (exact affine corner bound), compact, render survivors
// over the 16x16 tile (wave = 8x8 sub-tile).
//   chunk!=0: store slice (if n>0), release cnt=n+1, exit.
//   chunk==0: keep own acc in registers, spin on 15 sibling cnts, sum their
//             slices, alpha/SSE for the tile, release tileFlag.
//   block 0:  additionally spins on all 256 tileFlags, reduces, plain-stores
//             out[0] (single writer -> no zero-init needed under 0xAA poison).
// Deadlock-free without dispatch-order assumptions: spinners <= 256 chip-wide
// vs >= 2048 co-resident block slots -> producers always schedulable.
// ---------------------------------------------------------------------------
__global__ __launch_bounds__(256, 8) void fused_kernel(
    const float* __restrict__ verts,     // (NUM_V,3)
    const int*   __restrict__ faces,     // (NUM_F,3)
    const float* __restrict__ cam,       // (3,)
    const float* __restrict__ image_ref, // (IMG_H*IMG_H)
    float* __restrict__ slices,
    int*   __restrict__ cnt,
    float* __restrict__ tileSSE,
    int*   __restrict__ tileFlag,
    float* __restrict__ out)
{
    __shared__ float sx[NUM_V], sy[NUM_V], sz[NUM_V];   // 6 KB
    __shared__ float4 sfA[FPC+4], sfB[FPC+4];
    __shared__ float  sfC[FPC+4];
    __shared__ int   scnt;
    __shared__ int   scc[NCHUNK];
    __shared__ float wsum[4];

    const int tid   = threadIdx.x;
    const int chunk = blockIdx.x & (NCHUNK-1);
    const int tile  = blockIdx.x / NCHUNK;

    if (tid == 0) scnt = 0;

    // ---- camera basis ----
    const float ex = cam[0], ey = cam[1], ez = cam[2];
    float inv = 1.0f / (sqrtf(ex*ex + ey*ey + ez*ez) + 1e-8f);
    const float zx = -ex*inv, zy = -ey*inv, zz = -ez*inv;
    float xxr = zz, xyr = 0.0f, xzr = -zx;    // cross((0,1,0), z)
    inv = 1.0f / (sqrtf(xxr*xxr + xyr*xyr + xzr*xzr) + 1e-8f);
    const float xx = xxr*inv, xy = xyr*inv, xz = xzr*inv;
    float yxr = zy*xz - zz*xy;
    float yyr = zz*xx - zx*xz;
    float yzr = zx*xy - zy*xx;
    inv = 1.0f / (sqrtf(yxr*yxr + yyr*yyr + yzr*yzr) + 1e-8f);
    const float yx = yxr*inv, yy = yyr*inv, yz = yzr*inv;

    // ---- project vertices (2 per thread) ----
    for (int v = tid; v < NUM_V; v += 256) {
        float px = verts[3*v+0] - ex;
        float py = verts[3*v+1] - ey;
        float pz = verts[3*v+2] - ez;
        float vx = xx*px + xy*py + xz*pz;
        float vy = yx*px + yy*py + yz*pz;
        float vz = zx*px + zy*py + zz*pz;
        float denom = 1.0f / (vz*TAN_T + 1e-8f);
        sx[v] = vx*denom;
        sy[v] = vy*denom;
        sz[v] = vz;
    }
    __syncthreads();   // covers scnt init too

    // ---- tile rect (pixel-center corners; d affine -> corners bound it) ----
    const int j0 = (tile & 15) * 16;
    const int i0 = (tile >> 4) * 16;
    const float xL = (j0 + 0.5f )*(2.0f/IMG_H) - 1.0f;
    const float xR = (j0 + 15.5f)*(2.0f/IMG_H) - 1.0f;
    const float yT = 1.0f - (i0 + 0.5f )*(2.0f/IMG_H);
    const float yB = 1.0f - (i0 + 15.5f)*(2.0f/IMG_H);

    // ---- cull + compact this chunk's faces (one per thread, tid<64) ----
    if (tid < FPC) {
        const int f = chunk*FPC + tid;
        int i0f = faces[3*f+0], i1f = faces[3*f+1], i2f = faces[3*f+2];
        float ax = sx[i0f], ay = sy[i0f], z0 = sz[i0f];
        float bx = sx[i1f], by = sy[i1f], z1 = sz[i1f];
        float cx = sx[i2f], cy = sy[i2f], z2 = sz[i2f];
        bool keep = (z0 > 0.001f && z1 > 0.001f && z2 > 0.001f);

        float A[3], B[3], C[3];   // scaled by 100 = sqrt(1/SIGMA)
        const float px_[3] = {ax, bx, cx}, py_[3] = {ay, by, cy};
        const float qx_[3] = {bx, cx, ax}, qy_[3] = {by, cy, ay};
        #pragma unroll
        for (int k = 0; k < 3; ++k) {
            float eex = qx_[k] - px_[k];
            float eey = qy_[k] - py_[k];
            float il = 100.0f / (sqrtf(eex*eex + eey*eey) + 1e-8f);
            A[k] = eex*il;
            B[k] = eey*il;
            C[k] = (eex*py_[k] - eey*px_[k])*il;
        }

        if (keep) {
            float minmx = 3.0e38f, maxmn = -3.0e38f;
            #pragma unroll
            for (int k = 0; k < 3; ++k) {
                float dTL = A[k]*yT - B[k]*xL - C[k];
                float dTR = A[k]*yT - B[k]*xR - C[k];
                float dBL = A[k]*yB - B[k]*xL - C[k];
                float dBR = A[k]*yB - B[k]*xR - C[k];
                float mx = fmaxf(fmaxf(dTL, dTR), fmaxf(dBL, dBR));
                float mn = fminf(fminf(dTL, dTR), fminf(dBL, dBR));
                minmx = fminf(minmx, mx);
                maxmn = fmaxf(maxmn, mn);
            }
            keep = !((minmx <= DCULL_S) && (maxmn >= -DCULL_S));
        }
        if (keep) {
            int s = atomicAdd(&scnt, 1);
            sfA[s] = make_float4(A[0], B[0], C[0], A[1]);
            sfB[s] = make_float4(B[1], C[1], A[2], B[2]);
            sfC[s] = C[2];
        }
    }
    __syncthreads();

    const int n = scnt;
    const bool isFin = (chunk == 0);

    // ---- pixel for this thread: wave = 8x8 sub-tile ----
    const int w = tid >> 6, l = tid & 63;
    const int lj = (w & 1)*8 + (l & 7);
    const int li = (w >> 1)*8 + (l >> 3);
    const int idx = li*16 + lj;               // slice index (same for all chunks)
    const float qx = (j0 + lj + 0.5f)*(2.0f/IMG_H) - 1.0f;
    const float qy = 1.0f - (i0 + li + 0.5f)*(2.0f/IMG_H);

    float acc = 0.0f;
    if (n > 0) {
        // pad to multiple of 4 with zero-contribution sentinels
        const int npad = (4 - (n & 3)) & 3;
        if (tid < npad) {
            const int s = n + tid;
            sfA[s] = make_float4(0.0f, 0.0f, 1e30f, 0.0f);
            sfB[s] = make_float4(0.0f, -1e30f, 0.0f, 0.0f);
            sfC[s] = 0.0f;
        }
        __syncthreads();
        const int ng = (n + 3) & ~3;

        for (int g = 0; g < ng; g += 4) {
            float dist4[4];
            #pragma unroll
            for (int u = 0; u < 4; ++u) {
                float4 w0 = sfA[g+u];
                float4 w1 = sfB[g+u];
                float  c2 = sfC[g+u];
                float d0 = fmaf(w0.x, qy, -fmaf(w0.y, qx, w0.z));
                float d1 = fmaf(w0.w, qy, -fmaf(w1.x, qx, w1.y));
                float d2 = fmaf(w1.z, qy, -fmaf(w1.w, qx, c2));
                float dmin = fminf(fminf(d0, d1), d2);
                float dmax = fmaxf(fmaxf(d0, d1), d2);
                dist4[u] = fmaxf(dmin, -dmax);   // = 100 * true dist
            }
            float gm = fmaxf(fmaxf(dist4[0], dist4[1]), fmaxf(dist4[2], dist4[3]));
            if (__any(gm > DCULL_S)) {
                #pragma unroll
                for (int u = 0; u < 4; ++u) {
                    float dist = dist4[u];
                    float s  = dist * fabsf(dist);     // true dist*|dist|/SIGMA
                    float e2 = __builtin_exp2f(-fabsf(s) * 1.44269504f);
                    float lg = __builtin_log2f(1.0f + e2);
                    float sp = fmaf(lg, 0.69314718f, fmaxf(s, 0.0f));
                    acc += fmaxf(-sp, LOG_EPS);
                }
            }
        }
    }

    if (!isFin) {
        // producer: publish slice (if any) then cnt = n+1 (release)
        if (n > 0) slices[(tile*NCHUNK + chunk)*256 + idx] = acc;
        __syncthreads();            // barrier drains vmcnt -> stores in flight done
        if (tid == 0) {
            __threadfence();
            st_release(&cnt[tile*NCHUNK + chunk], n + 1);
        }
        return;
    }

    // ---- tile finalizer (chunk 0): wait for 15 siblings ----
    if (tid >= 1 && tid < NCHUNK) {
        int v;
        while ((v = ld_acquire(&cnt[tile*NCHUNK + tid])) < 1)
            __builtin_amdgcn_s_sleep(2);
        scc[tid] = v - 1;           // sibling survivor count
    }
    __syncthreads();
    __threadfence();                // invalidate before reading remote slices

    float lsum = acc;               // own chunk's contribution (registers)
    #pragma unroll
    for (int c = 1; c < NCHUNK; ++c)
        if (scc[c] > 0) lsum += slices[(tile*NCHUNK + c)*256 + idx];

    float alpha = 1.0f - __expf(lsum);
    float diff  = image_ref[(i0 + li)*IMG_H + (j0 + lj)] - alpha;
    float sq = diff * diff;
    #pragma unroll
    for (int off = 32; off > 0; off >>= 1) sq += __shfl_down(sq, off, 64);
    if ((tid & 63) == 0) wsum[tid >> 6] = sq;
    __syncthreads();
    if (tid == 0) {
        tileSSE[tile] = (wsum[0] + wsum[1]) + (wsum[2] + wsum[3]);
        __threadfence();
        st_release(&tileFlag[tile], 1);
    }
    if (tile != 0) return;

    // ---- global finalizer (block 0): wait for all 256 tiles ----
    if (tid >= 1) {
        while (ld_acquire(&tileFlag[tid]) < 1)
            __builtin_amdgcn_s_sleep(4);
    }
    __syncthreads();
    __threadfence();

    float sv = tileSSE[tid];        // tid 0 reads its own tile's value
    #pragma unroll
    for (int off = 32; off > 0; off >>= 1) sv += __shfl_down(sv, off, 64);
    if ((tid & 63) == 0) wsum[tid >> 6] = sv;
    __syncthreads();
    if (tid == 0) {
        float dist = sqrtf(ex*ex + ey*ey + ez*ez);
        float pen  = fmaxf(6.0f - dist, 0.0f);
        float total = (wsum[0] + wsum[1]) + (wsum[2] + wsum[3]);
        out[0] = total * (1.0f + pen);   // single writer, plain store
    }
}

extern "C" void kernel_launch(void* const* d_in, const int* in_sizes, int n_in,
                              void* d_out, int out_size, void* d_ws, size_t ws_size,
                              hipStream_t stream)
{
    const float* verts     = (const float*)d_in[0];  // (1,512,3)
    const int*   faces     = (const int*)  d_in[1];  // (1,1024,3)
    const float* image_ref = (const float*)d_in[2];  // (256,256)
    const float* cam       = (const float*)d_in[3];  // (3,)

    char* ws = (char*)d_ws;
    float* slices   = (float*)ws;                               // 4 MB
    int*   cnt      = (int*)  (ws + 256*NCHUNK*256*4);          // 16 KB
    float* tileSSE  = (float*)(ws + 256*NCHUNK*256*4 + 256*NCHUNK*4);
    int*   tileFlag = (int*)  (ws + 256*NCHUNK*256*4 + 256*NCHUNK*4 + 256*4);
    float* out      = (float*)d_out;

    fused_kernel<<<256*NCHUNK, 256, 0, stream>>>(verts, faces, cam, image_ref,
                                                 slices, cnt, tileSSE, tileFlag,
                                                 out);
}